// Round 1
// baseline (2155.817 us; speedup 1.0000x reference)
//
#include <hip/hip_runtime.h>

// Hungarian (Kuhn-Munkres, e-maxx shortest-augmenting-path form) for 32
// independent 128x128 L1-cost assignment problems.
// One block (128 threads = 2 waves) per problem; lane tid owns column j=tid+1.
// Cost entries are recomputed on the fly from LDS-staged points (no 64KB
// cost tile). Arithmetic order matches the JAX reference exactly:
//   cur = ((|dx|+|dy|) - u[i0]) - v[j]
// argmin tie-break = first (lowest) index, as jnp.argmin.

#define NN 128
#define BIGF 1e9f

__global__ __launch_bounds__(128) void hungarian_kernel(
    const float* __restrict__ preds,
    const float* __restrict__ targets,
    int* __restrict__ out)
{
    __shared__ float qx[NN], qy[NN], tx[NN], ty[NN];
    __shared__ float u[NN + 1], v[NN + 1], minv[NN + 1];
    __shared__ int   p[NN + 1], way[NN + 1], used[NN + 1];
    __shared__ float redv[2];
    __shared__ int   redi[2];
    __shared__ int   j0_s;

    const int prob = blockIdx.x;
    const int tid  = threadIdx.x;

    // Stage points for this problem (each 128 x 2 fp32, interleaved xy).
    qx[tid] = preds[(prob * NN + tid) * 2 + 0];
    qy[tid] = preds[(prob * NN + tid) * 2 + 1];
    tx[tid] = targets[(prob * NN + tid) * 2 + 0];
    ty[tid] = targets[(prob * NN + tid) * 2 + 1];
    for (int k = tid; k <= NN; k += NN) { u[k] = 0.f; v[k] = 0.f; p[k] = 0; }
    __syncthreads();

    const float txv = tx[tid];
    const float tyv = ty[tid];
    const int   j   = tid + 1;   // 1-indexed column owned by this lane

    for (int i = 0; i < NN; ++i) {
        for (int k = tid; k <= NN; k += NN) { minv[k] = BIGF; used[k] = 0; way[k] = 0; }
        if (tid == 0) { p[0] = i + 1; j0_s = 0; }
        __syncthreads();

        while (true) {
            const int j0 = j0_s;
            if (p[j0] == 0) break;           // uniform: shared state, post-barrier
            if (tid == 0) used[j0] = 1;
            __syncthreads();                  // B1: used[j0] visible to all lanes

            const int   i0 = p[j0];
            const float qxi = qx[i0 - 1];
            const float qyi = qy[i0 - 1];
            const float ui  = u[i0];

            // reduced cost of (row i0-1, col j-1); reference op order preserved
            float cur = ((fabsf(qxi - txv) + fabsf(qyi - tyv)) - ui) - v[j];
            if (used[j]) cur = BIGF;
            if (cur < minv[j]) { minv[j] = cur; way[j] = j0; }

            // argmin over masked minv (first-index tie-break, like jnp.argmin)
            float val = used[j] ? BIGF : minv[j];
            int   idx = tid;
            #pragma unroll
            for (int s = 32; s > 0; s >>= 1) {
                float v2 = __shfl_xor(val, s, 64);
                int   i2 = __shfl_xor(idx, s, 64);
                if (v2 < val || (v2 == val && i2 < idx)) { val = v2; idx = i2; }
            }
            if ((tid & 63) == 0) { redv[tid >> 6] = val; redi[tid >> 6] = idx; }
            __syncthreads();                  // B2: cross-wave combine

            float va = redv[0], vb = redv[1];
            int   ia = redi[0], ib = redi[1];
            float delta; int jm;
            if (vb < va || (vb == va && ib < ia)) { delta = vb; jm = ib; }
            else                                  { delta = va; jm = ia; }
            const int j1 = jm + 1;

            // dual / minv updates; used columns have distinct p[k] (no races)
            for (int k = tid; k <= NN; k += NN) {
                if (used[k]) { u[p[k]] += delta; v[k] -= delta; }
                else         { minv[k] -= delta; }
            }
            if (tid == 0) j0_s = j1;
            __syncthreads();                  // B3: drain updates before next check
        }

        // augment along the alternating path recorded in `way`
        if (tid == 0) {
            int jj = j0_s;
            while (jj != 0) {
                int jn = way[jj];
                p[jj]  = p[jn];
                jj     = jn;
            }
        }
        __syncthreads();
    }

    // p[j] (j=1..N) is the 1-indexed row matched to column j-1.
    // row_to_col[p[j]-1] = j-1  ==  out[prob*N + row] = col
    out[prob * NN + (p[j] - 1)] = tid;
}

extern "C" void kernel_launch(void* const* d_in, const int* in_sizes, int n_in,
                              void* d_out, int out_size, void* d_ws, size_t ws_size,
                              hipStream_t stream) {
    const float* preds   = (const float*)d_in[0];   // (4,8,128,2) fp32
    const float* targets = (const float*)d_in[1];   // (4,8,128,2) fp32
    int* out = (int*)d_out;                         // (4,8,128) int32

    hungarian_kernel<<<32, 128, 0, stream>>>(preds, targets, out);
}

// Round 2
// 883.207 us; speedup vs baseline: 2.4409x; 2.4409x over previous
//
#include <hip/hip_runtime.h>

// Hungarian (e-maxx shortest-augmenting-path), 32 independent 128x128 L1
// assignment problems. ONE WAVE (64 lanes) per problem, 2 columns per lane.
// Fully wave-synchronous: no __syncthreads, no LDS. All state in registers:
//   per column j (2 slots/lane): v[j], minv[j], way[j], used[j], p[j],
//   w[j] = u[p[j]] (row-potential cache), qc[j] = pred coords of row p[j].
// Row-indexed data (u[i0], q[i0]) is fetched via uniform v_readlane from the
// owner lane of column j0. Argmin = packed (orderable-float<<32 | col) u64
// DPP min-reduce (row_shr 1/2/4/8, row_bcast15/31) -> readlane 63.
// FP op order matches the JAX reference exactly: ((|dx|+|dy|) - u[i0]) - v[j];
// packed-key min == first-index argmin (monotone bijection, no -0.0 arises).

#define NN 128
#define BIGF 1e9f

__device__ __forceinline__ uint32_t fflip(float x) {
    uint32_t b = __float_as_uint(x);
    return (b & 0x80000000u) ? ~b : (b | 0x80000000u);
}
__device__ __forceinline__ float funflip(uint32_t k) {
    uint32_t b = (k & 0x80000000u) ? (k ^ 0x80000000u) : ~k;
    return __uint_as_float(b);
}
__device__ __forceinline__ int rl_i(int x, int l) {
    return __builtin_amdgcn_readlane(x, l);
}
__device__ __forceinline__ float rl_f(float x, int l) {
    return __uint_as_float((uint32_t)__builtin_amdgcn_readlane((int)__float_as_uint(x), l));
}

template <int CTRL, int RM>
__device__ __forceinline__ uint64_t dpp_min_step(uint64_t k) {
    uint32_t lo = (uint32_t)k, hi = (uint32_t)(k >> 32);
    uint32_t plo = (uint32_t)__builtin_amdgcn_update_dpp((int)lo, (int)lo, CTRL, RM, 0xf, false);
    uint32_t phi = (uint32_t)__builtin_amdgcn_update_dpp((int)hi, (int)hi, CTRL, RM, 0xf, false);
    uint64_t pk = ((uint64_t)phi << 32) | plo;
    return pk < k ? pk : k;
}

// full-wave (64-lane) u64 min, result broadcast uniform via readlane(63)
__device__ __forceinline__ uint64_t wave_min64(uint64_t k) {
    k = dpp_min_step<0x111, 0xf>(k);  // row_shr:1
    k = dpp_min_step<0x112, 0xf>(k);  // row_shr:2
    k = dpp_min_step<0x114, 0xf>(k);  // row_shr:4
    k = dpp_min_step<0x118, 0xf>(k);  // row_shr:8
    k = dpp_min_step<0x142, 0xa>(k);  // row_bcast15 (rows 1,3)
    k = dpp_min_step<0x143, 0xc>(k);  // row_bcast31 (rows 2,3)
    uint32_t lo = (uint32_t)rl_i((int)(uint32_t)k, 63);
    uint32_t hi = (uint32_t)rl_i((int)(uint32_t)(k >> 32), 63);
    return ((uint64_t)hi << 32) | lo;
}

__global__ __launch_bounds__(64) void hungarian_kernel(
    const float* __restrict__ preds,
    const float* __restrict__ targets,
    int* __restrict__ out)
{
    const int prob = blockIdx.x;
    const int lane = threadIdx.x;

    const float2* p2 = (const float2*)preds + prob * NN;
    const float2* t2 = (const float2*)targets + prob * NN;

    // per-lane: pred rows {lane, lane+64}, target cols {lane+1, lane+65}
    float2 qa = p2[lane], qb = p2[lane + 64];
    float2 ta = t2[lane], tb = t2[lane + 64];
    const float qrx[2] = {qa.x, qb.x};
    const float qry[2] = {qa.y, qb.y};
    const float tx[2]  = {ta.x, tb.x};
    const float ty[2]  = {ta.y, tb.y};
    const int   col[2] = {lane + 1, lane + 65};

    float v_[2]  = {0.f, 0.f};   // column duals
    float w_[2]  = {0.f, 0.f};   // u[p[col]] cache (valid when p_ != 0)
    float qcx[2] = {0.f, 0.f};   // pred x of row p[col]
    float qcy[2] = {0.f, 0.f};   // pred y of row p[col]
    int   p_[2]  = {0, 0};       // matched row (1-indexed), 0 = free

    for (int i = 0; i < NN; ++i) {
        float minv[2] = {BIGF, BIGF};
        int   way_[2] = {0, 0};
        bool  used[2] = {false, false};
        float u_row   = 0.f;                    // u[i+1] (current row), starts 0

        // q coords of current row i (uniform, via readlane from row owner)
        const float qix0 = rl_f(qrx[0], i & 63), qix1 = rl_f(qrx[1], i & 63);
        const float qiy0 = rl_f(qry[0], i & 63), qiy1 = rl_f(qry[1], i & 63);
        const float qix = (i >> 6) ? qix1 : qix0;
        const float qiy = (i >> 6) ? qiy1 : qiy0;

        int   j0   = 0;      // current column in the alternating search
        float u_j0 = 0.f;    // u[p[j0]]; for j0=0: u[i+1] = 0
        float cqx  = qix;    // pred coords of row p[j0]
        float cqy  = qiy;

        for (int it = 0; it <= NN; ++it) {      // bounded: <= N+1 iterations
            // mark used[j0] (no-op for entry 0)
            used[0] = used[0] || (col[0] == j0);
            used[1] = used[1] || (col[1] == j0);

            // reduced costs + minv/way update + packed keys
            uint64_t keys[2];
            #pragma unroll
            for (int s = 0; s < 2; ++s) {
                float cur = ((fabsf(cqx - tx[s]) + fabsf(cqy - ty[s])) - u_j0) - v_[s];
                if (!used[s] && cur < minv[s]) { minv[s] = cur; way_[s] = j0; }
                float mval = used[s] ? BIGF : minv[s];
                keys[s] = ((uint64_t)fflip(mval) << 32) | (uint32_t)col[s];
            }
            uint64_t k = keys[1] < keys[0] ? keys[1] : keys[0];
            k = wave_min64(k);
            const int   j1    = (int)(uint32_t)k;       // argmin column (1-idx)
            const float delta = funflip((uint32_t)(k >> 32));

            // fetch (p, w, qc) of column j1 from owner lane (pre-update values;
            // u[p[j1]] is not touched by this iteration's dual update)
            const int src  = (j1 - 1) & 63;
            const int slot = (j1 - 1) >> 6;
            int   pa = rl_i(p_[0], src),  pb = rl_i(p_[1], src);
            float wa = rl_f(w_[0], src),  wb = rl_f(w_[1], src);
            float xa = rl_f(qcx[0], src), xb = rl_f(qcx[1], src);
            float ya = rl_f(qcy[0], src), yb = rl_f(qcy[1], src);
            const int   i0n = slot ? pb : pa;
            const float u_n = slot ? wb : wa;
            const float xn  = slot ? xb : xa;
            const float yn  = slot ? yb : ya;

            // dual / minv updates (reference formulas)
            #pragma unroll
            for (int s = 0; s < 2; ++s) {
                if (used[s]) { v_[s] -= delta; w_[s] += delta; }
                else         { minv[s] -= delta; }
            }
            u_row += delta;                     // used[0]: u[i+1] += delta

            j0 = j1; u_j0 = u_n; cqx = xn; cqy = yn;
            if (i0n == 0) break;                // column j1 is free -> augment
        }

        // augment: shuffle (p, w, qc) along the alternating path in `way`
        int jj = j0;
        for (int it = 0; it <= NN; ++it) {
            const int wsrc  = (jj - 1) & 63;
            const int wslot = (jj - 1) >> 6;
            const int wa0 = rl_i(way_[0], wsrc), wa1 = rl_i(way_[1], wsrc);
            const int jn  = wslot ? wa1 : wa0;   // uniform

            int pn; float wn, xn, yn;
            if (jn == 0) {                        // path root: current row
                pn = i + 1; wn = u_row; xn = qix; yn = qiy;
            } else {
                const int s2  = (jn - 1) & 63;
                const int sl2 = (jn - 1) >> 6;
                int   paa = rl_i(p_[0], s2),  pbb = rl_i(p_[1], s2);
                float waa = rl_f(w_[0], s2),  wbb = rl_f(w_[1], s2);
                float xaa = rl_f(qcx[0], s2), xbb = rl_f(qcx[1], s2);
                float yaa = rl_f(qcy[0], s2), ybb = rl_f(qcy[1], s2);
                pn = sl2 ? pbb : paa; wn = sl2 ? wbb : waa;
                xn = sl2 ? xbb : xaa; yn = sl2 ? ybb : yaa;
            }
            if (col[0] == jj) { p_[0] = pn; w_[0] = wn; qcx[0] = xn; qcy[0] = yn; }
            if (col[1] == jj) { p_[1] = pn; w_[1] = wn; qcx[1] = xn; qcy[1] = yn; }
            jj = jn;
            if (jj == 0) break;
        }
    }

    // p_[s] = row matched to column col[s]; out[row] = col (0-indexed)
    out[prob * NN + p_[0] - 1] = col[0] - 1;
    out[prob * NN + p_[1] - 1] = col[1] - 1;
}

extern "C" void kernel_launch(void* const* d_in, const int* in_sizes, int n_in,
                              void* d_out, int out_size, void* d_ws, size_t ws_size,
                              hipStream_t stream) {
    const float* preds   = (const float*)d_in[0];   // (4,8,128,2) fp32
    const float* targets = (const float*)d_in[1];   // (4,8,128,2) fp32
    int* out = (int*)d_out;                         // (4,8,128) int32

    hungarian_kernel<<<32, 64, 0, stream>>>(preds, targets, out);
}

// Round 4
// 616.092 us; speedup vs baseline: 3.4992x; 1.4336x over previous
//
#include <hip/hip_runtime.h>

// Hungarian (e-maxx shortest-augmenting-path), 32 independent 128x128 L1
// assignment problems. ONE WAVE per problem, 2 columns per lane, zero LDS,
// zero barriers, bit-exact fp trajectory vs the JAX reference (v starts 0;
// op order ((|dx|+|dy|) - u[i0]) - v[j]; update forms v-=du / u+=du /
// minv-=where(used,0,delta) match the reference's vectorized ops exactly).
//
// R3 lesson: any algorithmic change to the fp trajectory (e.g. JV column
// reduction) flips near-tie assignments vs the reference -> FAIL. Only
// value-preserving instruction restructuring is admissible.
//
// vs R2 (837 us):
//  * argmin = one f32 v_min DPP chain (row_shr 1/2/4/8, bcast15/31) +
//    readlane(63) + two ballots + ffs  (first-index argmin, jnp semantics;
//    +-0 ties compare equal both ways)  -- replaces packed-u64 DPP min.
//  * fetch of column j1's row state: cndmask-select then single readlane per
//    field (4+4 ops), results are SGPRs feeding the next cost chain.
//  * first search step of each row specialized (j0=0, nothing used).

#define NN 128
#define BIGF 1e9f

__device__ __forceinline__ int rl_i(int x, int l) {
    return __builtin_amdgcn_readlane(x, l);
}
__device__ __forceinline__ float rl_f(float x, int l) {
    return __uint_as_float((uint32_t)__builtin_amdgcn_readlane((int)__float_as_uint(x), l));
}

template <int CTRL, int RM>
__device__ __forceinline__ float dpp_min_f(float x) {
    int xi = (int)__float_as_uint(x);
    float s = __uint_as_float((uint32_t)__builtin_amdgcn_update_dpp(xi, xi, CTRL, RM, 0xf, false));
    return fminf(x, s);
}

// full-wave (64-lane) f32 min, made uniform via readlane(63)
__device__ __forceinline__ float wave_min_f(float x) {
    x = dpp_min_f<0x111, 0xf>(x);  // row_shr:1
    x = dpp_min_f<0x112, 0xf>(x);  // row_shr:2
    x = dpp_min_f<0x114, 0xf>(x);  // row_shr:4
    x = dpp_min_f<0x118, 0xf>(x);  // row_shr:8
    x = dpp_min_f<0x142, 0xa>(x);  // row_bcast15 (rows 1,3)
    x = dpp_min_f<0x143, 0xc>(x);  // row_bcast31 (rows 2,3)
    return rl_f(x, 63);
}

__global__ __launch_bounds__(64) void hungarian_kernel(
    const float* __restrict__ preds,
    const float* __restrict__ targets,
    int* __restrict__ out)
{
    const int prob = blockIdx.x;
    const int lane = threadIdx.x;

    const float2* p2 = (const float2*)preds + prob * NN;
    const float2* t2 = (const float2*)targets + prob * NN;

    float2 qa = p2[lane], qb = p2[lane + 64];
    float2 ta = t2[lane], tb = t2[lane + 64];
    const float qrx[2] = {qa.x, qb.x};
    const float qry[2] = {qa.y, qb.y};
    const float tx[2]  = {ta.x, tb.x};
    const float ty[2]  = {ta.y, tb.y};
    const int   col[2] = {lane + 1, lane + 65};

    float v_[2]  = {0.f, 0.f};   // column duals (reference trajectory: start 0)
    float w_[2]  = {0.f, 0.f};   // u[p[col]] cache (valid when p_ != 0)
    float qcx[2] = {0.f, 0.f};   // pred x of row p[col]
    float qcy[2] = {0.f, 0.f};   // pred y of row p[col]
    int   p_[2]  = {0, 0};       // matched row (1-indexed), 0 = free

    for (int i = 0; i < NN; ++i) {
        // coords of current row i (uniform via readlane)
        const float qix = rl_f((i & 64) ? qrx[1] : qrx[0], i & 63);
        const float qiy = rl_f((i & 64) ? qry[1] : qry[0], i & 63);

        // ---- specialized first search step: j0 = 0, nothing used ----
        // cur = (cost - u[i+1]) - v, u[i+1] = +0 -> cost - v (bit-identical)
        float minv[2];
        int   way_[2] = {0, 0};
        bool  used[2] = {false, false};
        minv[0] = (fabsf(qix - tx[0]) + fabsf(qiy - ty[0])) - v_[0];
        minv[1] = (fabsf(qix - tx[1]) + fabsf(qiy - ty[1])) - v_[1];

        float m     = fminf(minv[0], minv[1]);
        float delta = wave_min_f(m);
        unsigned long long b0 = __ballot(minv[0] == delta);
        unsigned long long b1 = __ballot(minv[1] == delta);
        int j1 = b0 ? (int)__ffsll((long long)b0) : 64 + (int)__ffsll((long long)b1);

        int  src = (j1 - 1) & 63;
        bool hi  = ((j1 - 1) >> 6) != 0;
        int   i0n = rl_i(hi ? p_[1] : p_[0], src);
        float u_n = rl_f(hi ? w_[1] : w_[0], src);
        float cqx = rl_f(hi ? qcx[1] : qcx[0], src);
        float cqy = rl_f(hi ? qcy[1] : qcy[0], src);

        // step-0 updates: no used columns -> v,w unchanged; minv -= delta
        minv[0] -= delta;
        minv[1] -= delta;
        float u_row = delta;          // u[i+1] = 0 + delta (exact)
        int   j0    = j1;
        float u_j0  = u_n;

        if (i0n != 0) {
            for (int it = 0; it < NN; ++it) {   // bounded for safety
                used[0] = used[0] | (col[0] == j0);
                used[1] = used[1] | (col[1] == j0);

                float mv[2];
                #pragma unroll
                for (int s = 0; s < 2; ++s) {
                    float cur = ((fabsf(cqx - tx[s]) + fabsf(cqy - ty[s])) - u_j0) - v_[s];
                    bool upd = (!used[s]) & (cur < minv[s]);
                    if (upd) { minv[s] = cur; way_[s] = j0; }
                    mv[s] = used[s] ? BIGF : minv[s];
                }

                m     = fminf(mv[0], mv[1]);
                delta = wave_min_f(m);
                b0 = __ballot(mv[0] == delta);
                b1 = __ballot(mv[1] == delta);
                j1 = b0 ? (int)__ffsll((long long)b0) : 64 + (int)__ffsll((long long)b1);

                src = (j1 - 1) & 63;
                hi  = ((j1 - 1) >> 6) != 0;
                i0n = rl_i(hi ? p_[1] : p_[0], src);
                u_n = rl_f(hi ? w_[1] : w_[0], src);
                float nqx = rl_f(hi ? qcx[1] : qcx[0], src);
                float nqy = rl_f(hi ? qcy[1] : qcy[0], src);

                // reference-exact vectorized updates:
                //   v -= du, u[p] += du (du = used?delta:0), minv -= used?0:delta
                #pragma unroll
                for (int s = 0; s < 2; ++s) {
                    float td = used[s] ? delta : 0.f;
                    v_[s]  -= td;
                    w_[s]  += td;
                    minv[s] -= used[s] ? 0.f : delta;
                }
                u_row += delta;

                j0 = j1; u_j0 = u_n; cqx = nqx; cqy = nqy;
                if (i0n == 0) break;
            }
        }

        // ---- augment: shuffle (p, w, qc) along the `way` chain from j0 ----
        int jj = j0;
        for (int it = 0; it <= NN; ++it) {
            const int  wsrc = (jj - 1) & 63;
            const bool whi  = ((jj - 1) >> 6) != 0;
            const int  jn   = rl_i(whi ? way_[1] : way_[0], wsrc);

            int pn; float wn, xn, yn;
            if (jn == 0) {                      // path root: current row
                pn = i + 1; wn = u_row; xn = qix; yn = qiy;
            } else {
                const int  s2 = (jn - 1) & 63;
                const bool h2 = ((jn - 1) >> 6) != 0;
                pn = rl_i(h2 ? p_[1] : p_[0], s2);
                wn = rl_f(h2 ? w_[1] : w_[0], s2);
                xn = rl_f(h2 ? qcx[1] : qcx[0], s2);
                yn = rl_f(h2 ? qcy[1] : qcy[0], s2);
            }
            if (col[0] == jj) { p_[0] = pn; w_[0] = wn; qcx[0] = xn; qcy[0] = yn; }
            if (col[1] == jj) { p_[1] = pn; w_[1] = wn; qcx[1] = xn; qcy[1] = yn; }
            jj = jn;
            if (jj == 0) break;
        }
    }

    // p_[s] = row matched to column col[s]; out[row] = col (0-indexed)
    out[prob * NN + p_[0] - 1] = col[0] - 1;
    out[prob * NN + p_[1] - 1] = col[1] - 1;
}

extern "C" void kernel_launch(void* const* d_in, const int* in_sizes, int n_in,
                              void* d_out, int out_size, void* d_ws, size_t ws_size,
                              hipStream_t stream) {
    const float* preds   = (const float*)d_in[0];   // (4,8,128,2) fp32
    const float* targets = (const float*)d_in[1];   // (4,8,128,2) fp32
    int* out = (int*)d_out;                         // (4,8,128) int32

    hungarian_kernel<<<32, 64, 0, stream>>>(preds, targets, out);
}